// Round 3
// baseline (8531.148 us; speedup 1.0000x reference)
//
#include <hip/hip_runtime.h>
#include <hip/hip_bf16.h>

// Problem constants (match reference)
#define NN 100000
#define DD 128
#define HH 256

// ---------------- degree / dinv ----------------

__global__ __launch_bounds__(256) void deg_kernel(const int* __restrict__ dst,
                                                  int* __restrict__ ideg, int E) {
    int e = blockIdx.x * 256 + threadIdx.x;
    if (e < E) atomicAdd(&ideg[dst[e]], 1);
}

__global__ __launch_bounds__(256) void dinv_kernel(float* __restrict__ dinv, int n) {
    int i = blockIdx.x * 256 + threadIdx.x;
    if (i < n) {
        int c = ((const int*)dinv)[i];
        dinv[i] = rsqrtf((float)c + 1.0f);
    }
}

// ---------------- GEMM with dinv row-scale epilogue ----------------
// C[r, c] = dinv[r] * sum_k A[r,k] * W[k,c]
// A: [Nrows, K] row-major. W: row stride WS (pass W+colbase for a col slice).
// C: row stride CS. Grid: (CS/64, ceil(Nrows/64)).
template <int K, int WS, int CS>
__global__ __launch_bounds__(256) void gemm_scale(const float* __restrict__ A,
                                                  const float* __restrict__ W,
                                                  const float* __restrict__ dinv,
                                                  float* __restrict__ C, int Nrows) {
    constexpr int BK = 64;
    __shared__ float At[BK][64 + 4];   // k-major
    __shared__ float Wt[BK][64 + 4];

    const int tid = threadIdx.x;
    const int tx = tid & 15, ty = tid >> 4;
    const int row0 = blockIdx.y * 64;
    const int col0 = blockIdx.x * 64;

    float acc[4][4] = {};

    for (int k0 = 0; k0 < K; k0 += BK) {
        // A tile: 64 rows x 64 k, coalesced float4 loads, transpose into LDS
#pragma unroll
        for (int i = 0; i < 4; ++i) {
            int r = (tid >> 4) + i * 16;          // 0..63
            int kv = (tid & 15) * 4;
            int grow = row0 + r;
            float4 v = make_float4(0.f, 0.f, 0.f, 0.f);
            if (grow < Nrows)
                v = *(const float4*)(A + (size_t)grow * K + k0 + kv);
            At[kv + 0][r] = v.x;
            At[kv + 1][r] = v.y;
            At[kv + 2][r] = v.z;
            At[kv + 3][r] = v.w;
        }
        // W tile: already k-major
#pragma unroll
        for (int i = 0; i < 4; ++i) {
            int k = (tid >> 4) + i * 16;
            int cv = (tid & 15) * 4;
            float4 v = *(const float4*)(W + (size_t)(k0 + k) * WS + col0 + cv);
            *(float4*)&Wt[k][cv] = v;
        }
        __syncthreads();
#pragma unroll
        for (int k = 0; k < BK; ++k) {
            float4 a = *(const float4*)&At[k][ty * 4];
            float4 b = *(const float4*)&Wt[k][tx * 4];
            float av[4] = {a.x, a.y, a.z, a.w};
            float bv[4] = {b.x, b.y, b.z, b.w};
#pragma unroll
            for (int i = 0; i < 4; ++i)
#pragma unroll
                for (int j = 0; j < 4; ++j)
                    acc[i][j] = fmaf(av[i], bv[j], acc[i][j]);
        }
        __syncthreads();
    }

#pragma unroll
    for (int i = 0; i < 4; ++i) {
        int r = row0 + ty * 4 + i;
        if (r < Nrows) {
            float s = dinv[r];
            float4 o;
            o.x = acc[i][0] * s;
            o.y = acc[i][1] * s;
            o.z = acc[i][2] * s;
            o.w = acc[i][3] * s;
            *(float4*)(C + (size_t)r * CS + col0 + tx * 4) = o;
        }
    }
}

// ---------------- edge scatter-add ----------------
// agg[dst] += y[src], 128 channels per edge, 32 lanes x float4.
// y: row stride 128 (compact). agg: row stride AS (128 for layer2/d_out,
// 256 for layer1 halves scattering into strided x).
template <int AS>
__global__ __launch_bounds__(256) void scatter128(const float* __restrict__ y,
                                                  float* __restrict__ agg,
                                                  const int* __restrict__ src,
                                                  const int* __restrict__ dst, int E) {
    int t = blockIdx.x * 256 + threadIdx.x;
    int e = t >> 5;
    int lane = t & 31;
    if (e >= E) return;
    int s = src[e];
    int d = dst[e];
    float4 v = *(const float4*)(y + (size_t)s * 128 + lane * 4);
    float* p = agg + (size_t)d * AS + lane * 4;
    unsafeAtomicAdd(p + 0, v.x);
    unsafeAtomicAdd(p + 1, v.y);
    unsafeAtomicAdd(p + 2, v.z);
    unsafeAtomicAdd(p + 3, v.w);
}

// ---------------- combine epilogues ----------------
// aggx (row stride AS) += y (stride 128); out = [relu](dinv*(agg+y)+b), in place on aggx
template <int AS, bool RELU>
__global__ __launch_bounds__(256) void combine128(float* __restrict__ aggx,
                                                  const float* __restrict__ y,
                                                  const float* __restrict__ dinv,
                                                  const float* __restrict__ b,
                                                  int total4) {
    int i = blockIdx.x * 256 + threadIdx.x;
    if (i >= total4) return;
    int idx = i * 4;           // index in compact [N,128] space
    int n = idx >> 7;
    int c = idx & 127;
    float s = dinv[n];
    float* ap = aggx + (size_t)n * AS + c;
    float4 a = *(const float4*)ap;
    float4 yy = *(const float4*)(y + idx);
    float4 bb = *(const float4*)(b + c);
    float4 o;
    o.x = fmaf(s, a.x + yy.x, bb.x);
    o.y = fmaf(s, a.y + yy.y, bb.y);
    o.z = fmaf(s, a.z + yy.z, bb.z);
    o.w = fmaf(s, a.w + yy.w, bb.w);
    if (RELU) {
        o.x = fmaxf(o.x, 0.f);
        o.y = fmaxf(o.y, 0.f);
        o.z = fmaxf(o.z, 0.f);
        o.w = fmaxf(o.w, 0.f);
    }
    *(float4*)ap = o;
}

extern "C" void kernel_launch(void* const* d_in, const int* in_sizes, int n_in,
                              void* d_out, int out_size, void* d_ws, size_t ws_size,
                              hipStream_t stream) {
    const float* emb = (const float*)d_in[0];
    const float* W1  = (const float*)d_in[1];
    const float* b1  = (const float*)d_in[2];
    const float* W2  = (const float*)d_in[3];
    const float* b2  = (const float*)d_in[4];
    const int*   ei  = (const int*)d_in[5];   // harness passes integers as int32

    const int N = NN;
    const int E = in_sizes[5] / 2;
    const int* src = ei;
    const int* dst = ei + E;

    // workspace layout (floats): dinv | x[N*256] | yh[N*128]   (~154 MB peak)
    float* ws = (float*)d_ws;
    float* dinv = ws;
    float* x    = ws + 100032;                 // N*HH floats
    float* yh   = x + (size_t)N * HH;          // N*128 floats, reused per half & as y2
    float* out  = (float*)d_out;

    // 1. degree + dinv
    hipMemsetAsync(dinv, 0, (size_t)N * sizeof(int), stream);
    deg_kernel<<<(E + 255) / 256, 256, 0, stream>>>(dst, (int*)dinv, E);
    dinv_kernel<<<(N + 255) / 256, 256, 0, stream>>>(dinv, N);

    // 2. layer 1, column-split into two 128-wide halves scattering into strided x
    hipMemsetAsync(x, 0, (size_t)N * HH * sizeof(float), stream);
    const int scatterBlocks = (int)(((long long)E * 32 + 255) / 256);
    const int comb4 = N * 128 / 4;
    for (int h = 0; h < 2; ++h) {
        gemm_scale<DD, HH, 128><<<dim3(2, (N + 63) / 64), 256, 0, stream>>>(
            emb, W1 + h * 128, dinv, yh, N);
        scatter128<HH><<<scatterBlocks, 256, 0, stream>>>(yh, x + h * 128, src, dst, E);
        combine128<HH, true><<<(comb4 + 255) / 256, 256, 0, stream>>>(
            x + h * 128, yh, dinv, b1 + h * 128, comb4);
    }

    // 3. layer 2: y2 reuses yh; aggregate directly in d_out
    hipMemsetAsync(out, 0, (size_t)N * DD * sizeof(float), stream);
    gemm_scale<HH, DD, 128><<<dim3(2, (N + 63) / 64), 256, 0, stream>>>(x, W2, dinv, yh, N);
    scatter128<DD><<<scatterBlocks, 256, 0, stream>>>(yh, out, src, dst, E);
    combine128<DD, false><<<(comb4 + 255) / 256, 256, 0, stream>>>(out, yh, dinv, b2, comb4);
}

// Round 4
// 923.895 us; speedup vs baseline: 9.2339x; 9.2339x over previous
//
#include <hip/hip_runtime.h>
#include <hip/hip_bf16.h>

#define NN 100000
#define DD 128
#define HH 256

// ---------------- degree / dinv ----------------

__global__ __launch_bounds__(256) void deg_kernel(const int* __restrict__ dst,
                                                  int* __restrict__ ideg, int E) {
    int e = blockIdx.x * 256 + threadIdx.x;
    if (e < E) atomicAdd(&ideg[dst[e]], 1);
}

__global__ __launch_bounds__(256) void dinv_kernel(float* __restrict__ dinv, int n) {
    int i = blockIdx.x * 256 + threadIdx.x;
    if (i < n) {
        int c = ((const int*)dinv)[i];
        dinv[i] = rsqrtf((float)c + 1.0f);
    }
}

// ---------------- CSR build: 3-kernel exclusive scan + bucket fill ----------------

__global__ __launch_bounds__(256) void scan_block(const int* __restrict__ deg,
                                                  int* __restrict__ part,
                                                  int* __restrict__ bsum, int n) {
    __shared__ int s[256];
    int i = blockIdx.x * 256 + threadIdx.x;
    int v = (i < n) ? deg[i] : 0;
    s[threadIdx.x] = v;
    __syncthreads();
    for (int off = 1; off < 256; off <<= 1) {
        int t = (threadIdx.x >= off) ? s[threadIdx.x - off] : 0;
        __syncthreads();
        s[threadIdx.x] += t;
        __syncthreads();
    }
    if (i < n) part[i] = s[threadIdx.x] - v;     // exclusive
    if (threadIdx.x == 255) bsum[blockIdx.x] = s[255];
}

__global__ __launch_bounds__(512) void scan_tops(int* __restrict__ bsum, int nb) {
    __shared__ int s[512];
    int v = (threadIdx.x < nb) ? bsum[threadIdx.x] : 0;
    s[threadIdx.x] = v;
    __syncthreads();
    for (int off = 1; off < 512; off <<= 1) {
        int t = (threadIdx.x >= off) ? s[threadIdx.x - off] : 0;
        __syncthreads();
        s[threadIdx.x] += t;
        __syncthreads();
    }
    if (threadIdx.x < nb) bsum[threadIdx.x] = s[threadIdx.x] - v;   // exclusive
}

__global__ __launch_bounds__(256) void scan_add(int* __restrict__ offsets,
                                                const int* __restrict__ bsum,
                                                int* __restrict__ cursor, int n, int E) {
    int i = blockIdx.x * 256 + threadIdx.x;
    if (i < n) {
        int o = offsets[i] + bsum[blockIdx.x];
        offsets[i] = o;
        cursor[i] = o;
    }
    if (i == 0) offsets[n] = E;
}

__global__ __launch_bounds__(256) void bucket_fill(const int* __restrict__ src,
                                                   const int* __restrict__ dst,
                                                   int* __restrict__ cursor,
                                                   int* __restrict__ eidx, int E) {
    int e = blockIdx.x * 256 + threadIdx.x;
    if (e < E) {
        int p = atomicAdd(&cursor[dst[e]], 1);
        eidx[p] = src[e];
    }
}

// ---------------- GEMM with dinv row-scale epilogue ----------------
// C[r, c] = dinv[r] * sum_k A[r,k] * W[k,c]
template <int K, int WS, int CS>
__global__ __launch_bounds__(256) void gemm_scale(const float* __restrict__ A,
                                                  const float* __restrict__ W,
                                                  const float* __restrict__ dinv,
                                                  float* __restrict__ C, int Nrows) {
    constexpr int BK = 64;
    __shared__ float At[BK][64 + 4];
    __shared__ float Wt[BK][64 + 4];

    const int tid = threadIdx.x;
    const int tx = tid & 15, ty = tid >> 4;
    const int row0 = blockIdx.y * 64;
    const int col0 = blockIdx.x * 64;

    float acc[4][4] = {};

    for (int k0 = 0; k0 < K; k0 += BK) {
#pragma unroll
        for (int i = 0; i < 4; ++i) {
            int r = (tid >> 4) + i * 16;
            int kv = (tid & 15) * 4;
            int grow = row0 + r;
            float4 v = make_float4(0.f, 0.f, 0.f, 0.f);
            if (grow < Nrows)
                v = *(const float4*)(A + (size_t)grow * K + k0 + kv);
            At[kv + 0][r] = v.x;
            At[kv + 1][r] = v.y;
            At[kv + 2][r] = v.z;
            At[kv + 3][r] = v.w;
        }
#pragma unroll
        for (int i = 0; i < 4; ++i) {
            int k = (tid >> 4) + i * 16;
            int cv = (tid & 15) * 4;
            float4 v = *(const float4*)(W + (size_t)(k0 + k) * WS + col0 + cv);
            *(float4*)&Wt[k][cv] = v;
        }
        __syncthreads();
#pragma unroll
        for (int k = 0; k < BK; ++k) {
            float4 a = *(const float4*)&At[k][ty * 4];
            float4 b = *(const float4*)&Wt[k][tx * 4];
            float av[4] = {a.x, a.y, a.z, a.w};
            float bv[4] = {b.x, b.y, b.z, b.w};
#pragma unroll
            for (int i = 0; i < 4; ++i)
#pragma unroll
                for (int j = 0; j < 4; ++j)
                    acc[i][j] = fmaf(av[i], bv[j], acc[i][j]);
        }
        __syncthreads();
    }

#pragma unroll
    for (int i = 0; i < 4; ++i) {
        int r = row0 + ty * 4 + i;
        if (r < Nrows) {
            float s = dinv[r];
            float4 o;
            o.x = acc[i][0] * s;
            o.y = acc[i][1] * s;
            o.z = acc[i][2] * s;
            o.w = acc[i][3] * s;
            *(float4*)(C + (size_t)r * CS + col0 + tx * 4) = o;
        }
    }
}

// ---------------- CSR gather-reduce + fused epilogue ----------------
// One wave (64 lanes) per node, float2 per lane = 128 channels.
// out[node] = [relu]( dinv[node] * (y[node] + sum_{e in CSR(node)} y[eidx[e]]) + b )
// y row stride 128; out row stride AS (256 for layer-1 halves, 128 for layer-2).
template <int AS, bool RELU>
__global__ __launch_bounds__(256) void gather_agg(const float* __restrict__ y,
                                                  float* __restrict__ xout,
                                                  const int* __restrict__ offsets,
                                                  const int* __restrict__ eidx,
                                                  const float* __restrict__ dinv,
                                                  const float* __restrict__ b, int N) {
    int node = blockIdx.x * 4 + (threadIdx.x >> 6);
    if (node >= N) return;
    int c = (threadIdx.x & 63) * 2;
    const size_t cs = c;

    float2 acc = *(const float2*)(y + (size_t)node * 128 + cs);   // self loop
    float2 acc2 = make_float2(0.f, 0.f);

    int e = offsets[node];
    const int e1 = offsets[node + 1];
    for (; e + 1 < e1; e += 2) {
        int s0 = eidx[e];
        int s1 = eidx[e + 1];
        float2 v0 = *(const float2*)(y + (size_t)s0 * 128 + cs);
        float2 v1 = *(const float2*)(y + (size_t)s1 * 128 + cs);
        acc.x += v0.x; acc.y += v0.y;
        acc2.x += v1.x; acc2.y += v1.y;
    }
    if (e < e1) {
        int s0 = eidx[e];
        float2 v0 = *(const float2*)(y + (size_t)s0 * 128 + cs);
        acc.x += v0.x; acc.y += v0.y;
    }

    float s = dinv[node];
    float2 bb = *(const float2*)(b + c);
    float ox = fmaf(s, acc.x + acc2.x, bb.x);
    float oy = fmaf(s, acc.y + acc2.y, bb.y);
    if (RELU) { ox = fmaxf(ox, 0.f); oy = fmaxf(oy, 0.f); }
    *(float2*)(xout + (size_t)node * AS + cs) = make_float2(ox, oy);
}

extern "C" void kernel_launch(void* const* d_in, const int* in_sizes, int n_in,
                              void* d_out, int out_size, void* d_ws, size_t ws_size,
                              hipStream_t stream) {
    const float* emb = (const float*)d_in[0];
    const float* W1  = (const float*)d_in[1];
    const float* b1  = (const float*)d_in[2];
    const float* W2  = (const float*)d_in[3];
    const float* b2  = (const float*)d_in[4];
    const int*   ei  = (const int*)d_in[5];   // int32 per harness contract

    const int N = NN;
    const int E = in_sizes[5] / 2;
    const int* src = ei;
    const int* dst = ei + E;

    // workspace layout: dinv | x[N*256] | yh[N*128] | offsets | cursor | bsum | eidx
    float* ws = (float*)d_ws;
    float* dinv   = ws;
    float* x      = ws + 100032;
    float* yh     = x + (size_t)N * HH;
    int*  offsets = (int*)(yh + (size_t)N * DD);
    int*  cursor  = offsets + 100032;
    int*  bsum    = cursor + 100032;
    int*  eidx    = bsum + 512;
    float* out    = (float*)d_out;

    const int NB = (N + 255) / 256;   // 391 scan blocks

    // 1. degree (into dinv buffer as ints) + CSR build + dinv
    hipMemsetAsync(dinv, 0, (size_t)N * sizeof(int), stream);
    deg_kernel<<<(E + 255) / 256, 256, 0, stream>>>(dst, (int*)dinv, E);
    scan_block<<<NB, 256, 0, stream>>>((const int*)dinv, offsets, bsum, N);
    scan_tops<<<1, 512, 0, stream>>>(bsum, NB);
    scan_add<<<NB, 256, 0, stream>>>(offsets, bsum, cursor, N, E);
    bucket_fill<<<(E + 255) / 256, 256, 0, stream>>>(src, dst, cursor, eidx, E);
    dinv_kernel<<<(N + 255) / 256, 256, 0, stream>>>(dinv, N);

    const int aggBlocks = (N + 3) / 4;

    // 2. layer 1: two 128-wide column halves, gather-reduce straight into x
    for (int h = 0; h < 2; ++h) {
        gemm_scale<DD, HH, 128><<<dim3(2, (N + 63) / 64), 256, 0, stream>>>(
            emb, W1 + h * 128, dinv, yh, N);
        gather_agg<HH, true><<<aggBlocks, 256, 0, stream>>>(
            yh, x + h * 128, offsets, eidx, dinv, b1 + h * 128, N);
    }

    // 3. layer 2: gather-reduce straight into d_out
    gemm_scale<HH, DD, 128><<<dim3(2, (N + 63) / 64), 256, 0, stream>>>(x, W2, dinv, yh, N);
    gather_agg<DD, false><<<aggBlocks, 256, 0, stream>>>(
        yh, out, offsets, eidx, dinv, b2, N);
}

// Round 5
// 621.380 us; speedup vs baseline: 13.7293x; 1.4868x over previous
//
#include <hip/hip_runtime.h>
#include <hip/hip_bf16.h>

#define NN 100000
#define DD 128
#define HH 256

typedef _Float16 half_t;
typedef _Float16 half8 __attribute__((ext_vector_type(8)));
typedef _Float16 half4_t __attribute__((ext_vector_type(4)));
typedef _Float16 half2_t __attribute__((ext_vector_type(2)));
typedef float floatx4 __attribute__((ext_vector_type(4)));

// ---------------- degree / dinv ----------------

__global__ __launch_bounds__(256) void deg_kernel(const int* __restrict__ dst,
                                                  int* __restrict__ ideg, int E) {
    int e = blockIdx.x * 256 + threadIdx.x;
    if (e < E) atomicAdd(&ideg[dst[e]], 1);
}

__global__ __launch_bounds__(256) void dinv_kernel(float* __restrict__ dinv, int n) {
    int i = blockIdx.x * 256 + threadIdx.x;
    if (i < n) {
        int c = ((const int*)dinv)[i];
        dinv[i] = rsqrtf((float)c + 1.0f);
    }
}

// ---------------- CSR build ----------------

__global__ __launch_bounds__(256) void scan_block(const int* __restrict__ deg,
                                                  int* __restrict__ part,
                                                  int* __restrict__ bsum, int n) {
    __shared__ int s[256];
    int i = blockIdx.x * 256 + threadIdx.x;
    int v = (i < n) ? deg[i] : 0;
    s[threadIdx.x] = v;
    __syncthreads();
    for (int off = 1; off < 256; off <<= 1) {
        int t = (threadIdx.x >= off) ? s[threadIdx.x - off] : 0;
        __syncthreads();
        s[threadIdx.x] += t;
        __syncthreads();
    }
    if (i < n) part[i] = s[threadIdx.x] - v;
    if (threadIdx.x == 255) bsum[blockIdx.x] = s[255];
}

__global__ __launch_bounds__(512) void scan_tops(int* __restrict__ bsum, int nb) {
    __shared__ int s[512];
    int v = (threadIdx.x < nb) ? bsum[threadIdx.x] : 0;
    s[threadIdx.x] = v;
    __syncthreads();
    for (int off = 1; off < 512; off <<= 1) {
        int t = (threadIdx.x >= off) ? s[threadIdx.x - off] : 0;
        __syncthreads();
        s[threadIdx.x] += t;
        __syncthreads();
    }
    if (threadIdx.x < nb) bsum[threadIdx.x] = s[threadIdx.x] - v;
}

__global__ __launch_bounds__(256) void scan_add(int* __restrict__ offsets,
                                                const int* __restrict__ bsum,
                                                int* __restrict__ cursor, int n, int E) {
    int i = blockIdx.x * 256 + threadIdx.x;
    if (i < n) {
        int o = offsets[i] + bsum[blockIdx.x];
        offsets[i] = o;
        cursor[i] = o;
    }
    if (i == 0) offsets[n] = E;
}

__global__ __launch_bounds__(256) void bucket_fill(const int* __restrict__ src,
                                                   const int* __restrict__ dst,
                                                   int* __restrict__ cursor,
                                                   int* __restrict__ eidx, int E) {
    int e = blockIdx.x * 256 + threadIdx.x;
    if (e < E) {
        int p = atomicAdd(&cursor[dst[e]], 1);
        eidx[p] = src[e];
    }
}

// ---------------- fp32 -> fp16 converts ----------------

__global__ __launch_bounds__(256) void f2h4(const float* __restrict__ in,
                                            half_t* __restrict__ out, int n4) {
    int i = blockIdx.x * 256 + threadIdx.x;
    if (i < n4) {
        float4 v = ((const float4*)in)[i];
        half4_t o = {(half_t)v.x, (half_t)v.y, (half_t)v.z, (half_t)v.w};
        ((half4_t*)out)[i] = o;
    }
}

// Wt[c][k] = (half)W[k][c]
__global__ __launch_bounds__(256) void transpose_w(const float* __restrict__ W,
                                                   half_t* __restrict__ Wt, int K, int C) {
    int i = blockIdx.x * 256 + threadIdx.x;
    if (i < K * C) {
        int k = i / C, c = i - k * C;
        Wt[(size_t)c * K + k] = (half_t)W[i];
    }
}

// ---------------- MFMA fp16 GEMM with dinv row-scale ----------------
// C[r,c] = (half) dinv[r] * sum_k A[r,k]*Bt[c,k]
// A: [M,K] fp16 row-major. Bt: [CT,K] fp16 row-major (pre-transposed W).
// Grid: (CT/64, ceil(M/128)), 256 threads (4 waves; 2x2 wave grid of 64x32).
template <int K, int CT>
__global__ __launch_bounds__(256) void gemm_mfma(const half_t* __restrict__ A,
                                                 const half_t* __restrict__ Bt,
                                                 const float* __restrict__ dinv,
                                                 half_t* __restrict__ C, int M) {
    constexpr int BK = 64;
    constexpr int LDA = 72;   // halves; 144 B row stride -> free 2-way bank aliasing
    __shared__ __align__(16) half_t As[128][LDA];
    __shared__ __align__(16) half_t Bs[64][LDA];

    const int tid = threadIdx.x;
    const int wave = tid >> 6, lane = tid & 63;
    const int wr = wave >> 1, wc = wave & 1;
    const int row0 = blockIdx.y * 128;
    const int col0 = blockIdx.x * 64;
    const int lrow = lane & 15, kq = lane >> 4;

    floatx4 acc[4][2] = {};

    for (int k0 = 0; k0 < K; k0 += BK) {
        // stage A: 128 rows x 64 halves, half8 coalesced
#pragma unroll
        for (int i = 0; i < 4; ++i) {
            int r = (tid >> 3) + i * 32;
            int kk = (tid & 7) * 8;
            int gr = row0 + r;
            half8 v = {};
            if (gr < M) v = *(const half8*)(A + (size_t)gr * K + k0 + kk);
            *(half8*)&As[r][kk] = v;
        }
        // stage B: 64 cols x 64 halves
#pragma unroll
        for (int i = 0; i < 2; ++i) {
            int n = (tid >> 3) + i * 32;
            int kk = (tid & 7) * 8;
            half8 v = *(const half8*)(Bt + (size_t)(col0 + n) * K + k0 + kk);
            *(half8*)&Bs[n][kk] = v;
        }
        __syncthreads();
#pragma unroll
        for (int ks = 0; ks < 2; ++ks) {
            half8 af[4], bf[2];
#pragma unroll
            for (int i = 0; i < 4; ++i)
                af[i] = *(const half8*)&As[wr * 64 + i * 16 + lrow][ks * 32 + kq * 8];
#pragma unroll
            for (int j = 0; j < 2; ++j)
                bf[j] = *(const half8*)&Bs[wc * 32 + j * 16 + lrow][ks * 32 + kq * 8];
#pragma unroll
            for (int i = 0; i < 4; ++i)
#pragma unroll
                for (int j = 0; j < 2; ++j)
                    acc[i][j] = __builtin_amdgcn_mfma_f32_16x16x32_f16(af[i], bf[j], acc[i][j], 0, 0, 0);
        }
        __syncthreads();
    }

    // epilogue: C/D layout col=lane&15, row=(lane>>4)*4+reg
#pragma unroll
    for (int i = 0; i < 4; ++i) {
#pragma unroll
        for (int r = 0; r < 4; ++r) {
            int grow = row0 + wr * 64 + i * 16 + kq * 4 + r;
            if (grow < M) {
                float s = dinv[grow];
#pragma unroll
                for (int j = 0; j < 2; ++j) {
                    int gcol = col0 + wc * 32 + j * 16 + lrow;
                    C[(size_t)grow * CT + gcol] = (half_t)(acc[i][j][r] * s);
                }
            }
        }
    }
}

// ---------------- CSR gather-reduce + fused epilogue ----------------
// Layer 1: 256 channels fp16, one wave per node, half4 per lane. Out: x fp16 + relu.
__global__ __launch_bounds__(256) void gather_h(const half_t* __restrict__ y,
                                                half_t* __restrict__ xout,
                                                const int* __restrict__ offsets,
                                                const int* __restrict__ eidx,
                                                const float* __restrict__ dinv,
                                                const float* __restrict__ bias, int N) {
    int node = blockIdx.x * 4 + (threadIdx.x >> 6);
    if (node >= N) return;
    int c = (threadIdx.x & 63) * 4;

    half4_t sv = *(const half4_t*)(y + (size_t)node * HH + c);
    float a0 = (float)sv[0], a1 = (float)sv[1], a2 = (float)sv[2], a3 = (float)sv[3];
    float c0 = 0.f, c1 = 0.f, c2 = 0.f, c3 = 0.f;

    int e = offsets[node];
    const int e1 = offsets[node + 1];
    for (; e + 1 < e1; e += 2) {
        int s0 = eidx[e];
        int s1 = eidx[e + 1];
        half4_t v0 = *(const half4_t*)(y + (size_t)s0 * HH + c);
        half4_t v1 = *(const half4_t*)(y + (size_t)s1 * HH + c);
        a0 += (float)v0[0]; a1 += (float)v0[1]; a2 += (float)v0[2]; a3 += (float)v0[3];
        c0 += (float)v1[0]; c1 += (float)v1[1]; c2 += (float)v1[2]; c3 += (float)v1[3];
    }
    if (e < e1) {
        int s0 = eidx[e];
        half4_t v0 = *(const half4_t*)(y + (size_t)s0 * HH + c);
        a0 += (float)v0[0]; a1 += (float)v0[1]; a2 += (float)v0[2]; a3 += (float)v0[3];
    }

    float s = dinv[node];
    float4 bb = *(const float4*)(bias + c);
    float o0 = fmaxf(fmaf(s, a0 + c0, bb.x), 0.f);
    float o1 = fmaxf(fmaf(s, a1 + c1, bb.y), 0.f);
    float o2 = fmaxf(fmaf(s, a2 + c2, bb.z), 0.f);
    float o3 = fmaxf(fmaf(s, a3 + c3, bb.w), 0.f);
    half4_t o = {(half_t)o0, (half_t)o1, (half_t)o2, (half_t)o3};
    *(half4_t*)(xout + (size_t)node * HH + c) = o;
}

// Layer 2: 128 channels fp16 in, fp32 out (d_out), half2 per lane, no relu.
__global__ __launch_bounds__(256) void gather_d(const half_t* __restrict__ y,
                                                float* __restrict__ out,
                                                const int* __restrict__ offsets,
                                                const int* __restrict__ eidx,
                                                const float* __restrict__ dinv,
                                                const float* __restrict__ bias, int N) {
    int node = blockIdx.x * 4 + (threadIdx.x >> 6);
    if (node >= N) return;
    int c = (threadIdx.x & 63) * 2;

    half2_t sv = *(const half2_t*)(y + (size_t)node * DD + c);
    float a0 = (float)sv[0], a1 = (float)sv[1];
    float c0 = 0.f, c1 = 0.f;

    int e = offsets[node];
    const int e1 = offsets[node + 1];
    for (; e + 1 < e1; e += 2) {
        int s0 = eidx[e];
        int s1 = eidx[e + 1];
        half2_t v0 = *(const half2_t*)(y + (size_t)s0 * DD + c);
        half2_t v1 = *(const half2_t*)(y + (size_t)s1 * DD + c);
        a0 += (float)v0[0]; a1 += (float)v0[1];
        c0 += (float)v1[0]; c1 += (float)v1[1];
    }
    if (e < e1) {
        int s0 = eidx[e];
        half2_t v0 = *(const half2_t*)(y + (size_t)s0 * DD + c);
        a0 += (float)v0[0]; a1 += (float)v0[1];
    }

    float s = dinv[node];
    float2 bb = *(const float2*)(bias + c);
    float2 o;
    o.x = fmaf(s, a0 + c0, bb.x);
    o.y = fmaf(s, a1 + c1, bb.y);
    *(float2*)(out + (size_t)node * DD + c) = o;
}

extern "C" void kernel_launch(void* const* d_in, const int* in_sizes, int n_in,
                              void* d_out, int out_size, void* d_ws, size_t ws_size,
                              hipStream_t stream) {
    const float* emb = (const float*)d_in[0];
    const float* W1  = (const float*)d_in[1];
    const float* b1  = (const float*)d_in[2];
    const float* W2  = (const float*)d_in[3];
    const float* b2  = (const float*)d_in[4];
    const int*   ei  = (const int*)d_in[5];

    const int N = NN;
    const int E = in_sizes[5] / 2;
    const int* src = ei;
    const int* dst = ei + E;

    // workspace layout (bytes)
    char* w = (char*)d_ws;
    float*  dinv = (float*)w;  w += 100032 * 4;
    half_t* embh = (half_t*)w; w += (size_t)NN * DD * 2;   // later reused as y2
    half_t* xh   = (half_t*)w; w += (size_t)NN * HH * 2;
    half_t* y1h  = (half_t*)w; w += (size_t)NN * HH * 2;
    half_t* W1t  = (half_t*)w; w += (size_t)DD * HH * 2;
    half_t* W2t  = (half_t*)w; w += (size_t)HH * DD * 2;
    int* offsets = (int*)w;    w += 100032 * 4;
    int* cursor  = (int*)w;    w += 100032 * 4;
    int* bsum    = (int*)w;    w += 512 * 4;
    int* eidx    = (int*)w;
    float* out   = (float*)d_out;
    half_t* y2h  = embh;       // embh dead after GEMM1

    const int NB = (N + 255) / 256;

    // 1. degree + CSR + dinv
    hipMemsetAsync(dinv, 0, (size_t)N * sizeof(int), stream);
    deg_kernel<<<(E + 255) / 256, 256, 0, stream>>>(dst, (int*)dinv, E);
    scan_block<<<NB, 256, 0, stream>>>((const int*)dinv, offsets, bsum, N);
    scan_tops<<<1, 512, 0, stream>>>(bsum, NB);
    scan_add<<<NB, 256, 0, stream>>>(offsets, bsum, cursor, N, E);
    bucket_fill<<<(E + 255) / 256, 256, 0, stream>>>(src, dst, cursor, eidx, E);
    dinv_kernel<<<(N + 255) / 256, 256, 0, stream>>>(dinv, N);

    // 2. fp16 converts
    f2h4<<<(NN * DD / 4 + 255) / 256, 256, 0, stream>>>(emb, embh, NN * DD / 4);
    transpose_w<<<(DD * HH + 255) / 256, 256, 0, stream>>>(W1, W1t, DD, HH);
    transpose_w<<<(HH * DD + 255) / 256, 256, 0, stream>>>(W2, W2t, HH, DD);

    const int gy = (N + 127) / 128;
    const int aggBlocks = (N + 3) / 4;

    // 3. layer 1: y1 = (emb@W1)*dinv (fp16, full H), then one gather pass
    gemm_mfma<DD, HH><<<dim3(HH / 64, gy), 256, 0, stream>>>(embh, W1t, dinv, y1h, N);
    gather_h<<<aggBlocks, 256, 0, stream>>>(y1h, xh, offsets, eidx, dinv, b1, N);

    // 4. layer 2: y2 = (x@W2)*dinv, gather straight into d_out
    gemm_mfma<HH, DD><<<dim3(DD / 64, gy), 256, 0, stream>>>(xh, W2t, dinv, y2h, N);
    gather_d<<<aggBlocks, 256, 0, stream>>>(y2h, out, offsets, eidx, dinv, b2, N);
}

// Round 6
// 494.455 us; speedup vs baseline: 17.2536x; 1.2567x over previous
//
#include <hip/hip_runtime.h>
#include <hip/hip_bf16.h>

#define NN 100000
#define DD 128
#define HH 256

typedef _Float16 half_t;
typedef _Float16 half8 __attribute__((ext_vector_type(8)));
typedef _Float16 half4_t __attribute__((ext_vector_type(4)));
typedef float floatx4 __attribute__((ext_vector_type(4)));

// ---------------- degree / dinv ----------------

__global__ __launch_bounds__(256) void deg_kernel(const int* __restrict__ dst,
                                                  int* __restrict__ ideg, int E) {
    int e = blockIdx.x * 256 + threadIdx.x;
    if (e < E) atomicAdd(&ideg[dst[e]], 1);
}

__global__ __launch_bounds__(256) void dinv_kernel(float* __restrict__ dinv, int n) {
    int i = blockIdx.x * 256 + threadIdx.x;
    if (i < n) {
        int c = ((const int*)dinv)[i];
        dinv[i] = rsqrtf((float)c + 1.0f);
    }
}

// ---------------- CSR build ----------------

__global__ __launch_bounds__(256) void scan_block(const int* __restrict__ deg,
                                                  int* __restrict__ part,
                                                  int* __restrict__ bsum, int n) {
    __shared__ int s[256];
    int i = blockIdx.x * 256 + threadIdx.x;
    int v = (i < n) ? deg[i] : 0;
    s[threadIdx.x] = v;
    __syncthreads();
    for (int off = 1; off < 256; off <<= 1) {
        int t = (threadIdx.x >= off) ? s[threadIdx.x - off] : 0;
        __syncthreads();
        s[threadIdx.x] += t;
        __syncthreads();
    }
    if (i < n) part[i] = s[threadIdx.x] - v;
    if (threadIdx.x == 255) bsum[blockIdx.x] = s[255];
}

__global__ __launch_bounds__(512) void scan_tops(int* __restrict__ bsum, int nb) {
    __shared__ int s[512];
    int v = (threadIdx.x < nb) ? bsum[threadIdx.x] : 0;
    s[threadIdx.x] = v;
    __syncthreads();
    for (int off = 1; off < 512; off <<= 1) {
        int t = (threadIdx.x >= off) ? s[threadIdx.x - off] : 0;
        __syncthreads();
        s[threadIdx.x] += t;
        __syncthreads();
    }
    if (threadIdx.x < nb) bsum[threadIdx.x] = s[threadIdx.x] - v;
}

__global__ __launch_bounds__(256) void scan_add(int* __restrict__ offsets,
                                                const int* __restrict__ bsum,
                                                int* __restrict__ cursor, int n, int E) {
    int i = blockIdx.x * 256 + threadIdx.x;
    if (i < n) {
        int o = offsets[i] + bsum[blockIdx.x];
        offsets[i] = o;
        cursor[i] = o;
    }
    if (i == 0) offsets[n] = E;
}

__global__ __launch_bounds__(256) void bucket_fill(const int* __restrict__ src,
                                                   const int* __restrict__ dst,
                                                   int* __restrict__ cursor,
                                                   int* __restrict__ eidx, int E) {
    int e = blockIdx.x * 256 + threadIdx.x;
    if (e < E) {
        int p = atomicAdd(&cursor[dst[e]], 1);
        eidx[p] = src[e];
    }
}

// ---------------- fp32 -> fp16 convert with per-row dinv scale ----------------
// z[r,c] = (half)(emb[r,c] * dinv[r]); 128 ch/row, float4 granularity
__global__ __launch_bounds__(256) void f2h_scale(const float* __restrict__ in,
                                                 const float* __restrict__ dinv,
                                                 half_t* __restrict__ out, int n4) {
    int i = blockIdx.x * 256 + threadIdx.x;
    if (i < n4) {
        float s = dinv[i >> 5];          // (i*4)/128
        float4 v = ((const float4*)in)[i];
        half4_t o = {(half_t)(v.x * s), (half_t)(v.y * s), (half_t)(v.z * s), (half_t)(v.w * s)};
        ((half4_t*)out)[i] = o;
    }
}

// Wt[c][k] = (half)W[k][c]
__global__ __launch_bounds__(256) void transpose_w(const float* __restrict__ W,
                                                   half_t* __restrict__ Wt, int K, int C) {
    int i = blockIdx.x * 256 + threadIdx.x;
    if (i < K * C) {
        int k = i / C, c = i - k * C;
        Wt[(size_t)c * K + k] = (half_t)W[i];
    }
}

// ---------------- MFMA fp16 GEMM ----------------
// C[r,c] = epilogue( sum_k A[r,k]*Bt[c,k] )
// BIASRELU: relu(acc + bias[c]);  else: acc * dinv[r]
// A: [M,K] fp16. Bt: [CT,K] fp16 (pre-transposed W). Grid: (CT/64, ceil(M/128)).
template <int K, int CT, bool BIASRELU>
__global__ __launch_bounds__(256) void gemm_mfma(const half_t* __restrict__ A,
                                                 const half_t* __restrict__ Bt,
                                                 const float* __restrict__ dinv,
                                                 const float* __restrict__ bias,
                                                 half_t* __restrict__ C, int M) {
    constexpr int BK = 64;
    constexpr int LDA = 72;   // halves; 144 B stride -> free 2-way bank aliasing
    __shared__ __align__(16) half_t As[128][LDA];
    __shared__ __align__(16) half_t Bs[64][LDA];

    const int tid = threadIdx.x;
    const int wave = tid >> 6, lane = tid & 63;
    const int wr = wave >> 1, wc = wave & 1;
    const int row0 = blockIdx.y * 128;
    const int col0 = blockIdx.x * 64;
    const int lrow = lane & 15, kq = lane >> 4;

    floatx4 acc[4][2] = {};

    for (int k0 = 0; k0 < K; k0 += BK) {
#pragma unroll
        for (int i = 0; i < 4; ++i) {
            int r = (tid >> 3) + i * 32;
            int kk = (tid & 7) * 8;
            int gr = row0 + r;
            half8 v = {};
            if (gr < M) v = *(const half8*)(A + (size_t)gr * K + k0 + kk);
            *(half8*)&As[r][kk] = v;
        }
#pragma unroll
        for (int i = 0; i < 2; ++i) {
            int n = (tid >> 3) + i * 32;
            int kk = (tid & 7) * 8;
            half8 v = *(const half8*)(Bt + (size_t)(col0 + n) * K + k0 + kk);
            *(half8*)&Bs[n][kk] = v;
        }
        __syncthreads();
#pragma unroll
        for (int ks = 0; ks < 2; ++ks) {
            half8 af[4], bf[2];
#pragma unroll
            for (int i = 0; i < 4; ++i)
                af[i] = *(const half8*)&As[wr * 64 + i * 16 + lrow][ks * 32 + kq * 8];
#pragma unroll
            for (int j = 0; j < 2; ++j)
                bf[j] = *(const half8*)&Bs[wc * 32 + j * 16 + lrow][ks * 32 + kq * 8];
#pragma unroll
            for (int i = 0; i < 4; ++i)
#pragma unroll
                for (int j = 0; j < 2; ++j)
                    acc[i][j] = __builtin_amdgcn_mfma_f32_16x16x32_f16(af[i], bf[j], acc[i][j], 0, 0, 0);
        }
        __syncthreads();
    }

    // C/D layout: col = lane&15, row = (lane>>4)*4 + reg
#pragma unroll
    for (int i = 0; i < 4; ++i) {
#pragma unroll
        for (int r = 0; r < 4; ++r) {
            int grow = row0 + wr * 64 + i * 16 + kq * 4 + r;
            if (grow < M) {
                float s = BIASRELU ? 0.f : dinv[grow];
#pragma unroll
                for (int j = 0; j < 2; ++j) {
                    int gcol = col0 + wc * 32 + j * 16 + lrow;
                    float v = acc[i][j][r];
                    if (BIASRELU) v = fmaxf(v + bias[gcol], 0.f);
                    else          v = v * s;
                    C[(size_t)grow * CT + gcol] = (half_t)v;
                }
            }
        }
    }
}

// ---------------- CSR gather-reduce, 128 fp16 channels ----------------
// half-wave (32 lanes) per node, half4 per lane; acc = y[node] + sum y[eidx]
// OUT16: write (half)(dinv*acc)    else: write fp32 dinv*acc + bias
template <bool OUT16>
__global__ __launch_bounds__(256) void gather128(const half_t* __restrict__ y,
                                                 void* __restrict__ outv,
                                                 const int* __restrict__ offsets,
                                                 const int* __restrict__ eidx,
                                                 const float* __restrict__ dinv,
                                                 const float* __restrict__ bias, int N) {
    int node = blockIdx.x * 8 + (threadIdx.x >> 5);
    if (node >= N) return;
    int c = (threadIdx.x & 31) * 4;

    half4_t sv = *(const half4_t*)(y + (size_t)node * DD + c);   // self loop
    float a0 = (float)sv[0], a1 = (float)sv[1], a2 = (float)sv[2], a3 = (float)sv[3];
    float b0 = 0.f, b1_ = 0.f, b2_ = 0.f, b3 = 0.f;

    int e = offsets[node];
    const int e1 = offsets[node + 1];
    for (; e + 3 < e1; e += 4) {
        int s0 = eidx[e], s1 = eidx[e + 1], s2 = eidx[e + 2], s3 = eidx[e + 3];
        half4_t v0 = *(const half4_t*)(y + (size_t)s0 * DD + c);
        half4_t v1 = *(const half4_t*)(y + (size_t)s1 * DD + c);
        half4_t v2 = *(const half4_t*)(y + (size_t)s2 * DD + c);
        half4_t v3 = *(const half4_t*)(y + (size_t)s3 * DD + c);
        a0 += (float)v0[0]; a1 += (float)v0[1]; a2 += (float)v0[2]; a3 += (float)v0[3];
        b0 += (float)v1[0]; b1_ += (float)v1[1]; b2_ += (float)v1[2]; b3 += (float)v1[3];
        a0 += (float)v2[0]; a1 += (float)v2[1]; a2 += (float)v2[2]; a3 += (float)v2[3];
        b0 += (float)v3[0]; b1_ += (float)v3[1]; b2_ += (float)v3[2]; b3 += (float)v3[3];
    }
    for (; e < e1; ++e) {
        int s0 = eidx[e];
        half4_t v0 = *(const half4_t*)(y + (size_t)s0 * DD + c);
        a0 += (float)v0[0]; a1 += (float)v0[1]; a2 += (float)v0[2]; a3 += (float)v0[3];
    }

    float s = dinv[node];
    float o0 = s * (a0 + b0);
    float o1 = s * (a1 + b1_);
    float o2 = s * (a2 + b2_);
    float o3 = s * (a3 + b3);
    if (OUT16) {
        half4_t o = {(half_t)o0, (half_t)o1, (half_t)o2, (half_t)o3};
        *(half4_t*)((half_t*)outv + (size_t)node * DD + c) = o;
    } else {
        float4 bb = *(const float4*)(bias + c);
        float4 o = make_float4(o0 + bb.x, o1 + bb.y, o2 + bb.z, o3 + bb.w);
        *(float4*)((float*)outv + (size_t)node * DD + c) = o;
    }
}

extern "C" void kernel_launch(void* const* d_in, const int* in_sizes, int n_in,
                              void* d_out, int out_size, void* d_ws, size_t ws_size,
                              hipStream_t stream) {
    const float* emb = (const float*)d_in[0];
    const float* W1  = (const float*)d_in[1];
    const float* b1  = (const float*)d_in[2];
    const float* W2  = (const float*)d_in[3];
    const float* b2  = (const float*)d_in[4];
    const int*   ei  = (const int*)d_in[5];

    const int N = NN;
    const int E = in_sizes[5] / 2;
    const int* src = ei;
    const int* dst = ei + E;

    // workspace layout (bytes)
    char* w = (char*)d_ws;
    float*  dinv = (float*)w;  w += 100032 * 4;
    half_t* zh   = (half_t*)w; w += (size_t)NN * DD * 2;   // emb*dinv; reused as y2
    half_t* g1h  = (half_t*)w; w += (size_t)NN * DD * 2;   // aggregated z
    half_t* x1h  = (half_t*)w; w += (size_t)NN * HH * 2;   // layer-1 output
    half_t* W1t  = (half_t*)w; w += (size_t)DD * HH * 2;
    half_t* W2t  = (half_t*)w; w += (size_t)HH * DD * 2;
    int* offsets = (int*)w;    w += 100032 * 4;
    int* cursor  = (int*)w;    w += 100032 * 4;
    int* bsum    = (int*)w;    w += 512 * 4;
    int* eidx    = (int*)w;
    float* out   = (float*)d_out;
    half_t* y2h  = zh;         // zh dead after gather1

    const int NB = (N + 255) / 256;

    // 1. degree + CSR + dinv
    hipMemsetAsync(dinv, 0, (size_t)N * sizeof(int), stream);
    deg_kernel<<<(E + 255) / 256, 256, 0, stream>>>(dst, (int*)dinv, E);
    scan_block<<<NB, 256, 0, stream>>>((const int*)dinv, offsets, bsum, N);
    scan_tops<<<1, 512, 0, stream>>>(bsum, NB);
    scan_add<<<NB, 256, 0, stream>>>(offsets, bsum, cursor, N, E);
    bucket_fill<<<(E + 255) / 256, 256, 0, stream>>>(src, dst, cursor, eidx, E);
    dinv_kernel<<<(N + 255) / 256, 256, 0, stream>>>(dinv, N);

    // 2. z = emb * dinv[row] (fp16) + weight transposes
    f2h_scale<<<(NN * DD / 4 + 255) / 256, 256, 0, stream>>>(emb, dinv, zh, NN * DD / 4);
    transpose_w<<<(DD * HH + 255) / 256, 256, 0, stream>>>(W1, W1t, DD, HH);
    transpose_w<<<(HH * DD + 255) / 256, 256, 0, stream>>>(W2, W2t, HH, DD);

    const int gy = (N + 127) / 128;
    const int aggBlocks = (N + 7) / 8;

    // 3. layer 1: aggregate-first (g1 = dinv*(z_self + sum z_src)), then GEMM w/ bias+relu
    gather128<true><<<aggBlocks, 256, 0, stream>>>(zh, g1h, offsets, eidx, dinv, nullptr, N);
    gemm_mfma<DD, HH, true><<<dim3(HH / 64, gy), 256, 0, stream>>>(g1h, W1t, dinv, b1, x1h, N);

    // 4. layer 2: GEMM-first (y2 = (x1@W2)*dinv), gather straight into d_out (fp32)
    gemm_mfma<HH, DD, false><<<dim3(DD / 64, gy), 256, 0, stream>>>(x1h, W2t, dinv, nullptr, y2h, N);
    gather128<false><<<aggBlocks, 256, 0, stream>>>(y2h, (void*)out, offsets, eidx, dinv, b2, N);
}

// Round 7
// 403.682 us; speedup vs baseline: 21.1333x; 1.2249x over previous
//
#include <hip/hip_runtime.h>
#include <hip/hip_bf16.h>

#define NN 100000
#define DD 128
#define HH 256

#define NBKT 391   // ceil(NN/256) buckets of 256 nodes (bucket = dst>>8)
#define ABLK 128   // partition blocks for phases A/B

typedef _Float16 half_t;
typedef _Float16 half8 __attribute__((ext_vector_type(8)));
typedef _Float16 half4_t __attribute__((ext_vector_type(4)));
typedef float floatx4 __attribute__((ext_vector_type(4)));

// ---------------- CSR build, LDS-atomic counting sort ----------------

// Phase A: per-block bucket histogram; cnt[b*ABLK+blk], tot[b] (tot pre-zeroed)
__global__ __launch_bounds__(256) void hist_bkt(const int* __restrict__ dst,
                                                int* __restrict__ cnt,
                                                int* __restrict__ tot,
                                                int E, int epb) {
    __shared__ int h[NBKT];
    for (int i = threadIdx.x; i < NBKT; i += 256) h[i] = 0;
    __syncthreads();
    int base = blockIdx.x * epb;
    int end = min(base + epb, E);
    for (int e = base + (int)threadIdx.x; e < end; e += 256)
        atomicAdd(&h[dst[e] >> 8], 1);
    __syncthreads();
    for (int i = threadIdx.x; i < NBKT; i += 256) {
        int v = h[i];
        cnt[i * ABLK + blockIdx.x] = v;
        if (v) atomicAdd(&tot[i], v);
    }
}

// exclusive scan of tot[NBKT] -> bktStart[NBKT], bktStart[NBKT]=E
__global__ __launch_bounds__(512) void scan_bkt(const int* __restrict__ tot,
                                                int* __restrict__ bktStart, int E) {
    __shared__ int s[512];
    int t = threadIdx.x;
    int v = (t < NBKT) ? tot[t] : 0;
    s[t] = v;
    __syncthreads();
    for (int off = 1; off < 512; off <<= 1) {
        int u = (t >= off) ? s[t - off] : 0;
        __syncthreads();
        s[t] += u;
        __syncthreads();
    }
    if (t < NBKT) bktStart[t] = s[t] - v;
    if (t == 0) bktStart[NBKT] = E;
}

// per-bucket exclusive scan over blocks -> blockOff[b*ABLK+i]
__global__ __launch_bounds__(128) void scan_blkoff(const int* __restrict__ cnt,
                                                   const int* __restrict__ bktStart,
                                                   int* __restrict__ blockOff) {
    __shared__ int s[128];
    int b = blockIdx.x, t = threadIdx.x;
    int v = cnt[b * ABLK + t];
    s[t] = v;
    __syncthreads();
    for (int off = 1; off < 128; off <<= 1) {
        int u = (t >= off) ? s[t - off] : 0;
        __syncthreads();
        s[t] += u;
        __syncthreads();
    }
    blockOff[b * ABLK + t] = bktStart[b] + s[t] - v;
}

// Phase B: partition edges into bucket-ordered psrc/pdst (LDS cursors only)
__global__ __launch_bounds__(256) void part_edges(const int* __restrict__ src,
                                                  const int* __restrict__ dst,
                                                  const int* __restrict__ blockOff,
                                                  int* __restrict__ psrc,
                                                  int* __restrict__ pdst,
                                                  int E, int epb) {
    __shared__ int lbase[NBKT];
    for (int i = threadIdx.x; i < NBKT; i += 256)
        lbase[i] = blockOff[i * ABLK + blockIdx.x];
    __syncthreads();
    int base = blockIdx.x * epb;
    int end = min(base + epb, E);
    for (int e = base + (int)threadIdx.x; e < end; e += 256) {
        int d = dst[e];
        int p = atomicAdd(&lbase[d >> 8], 1);
        psrc[p] = src[e];
        pdst[p] = d;
    }
}

// Phase C: per-bucket: node counts -> offsets + dinv + eidx fill (LDS cursors)
__global__ __launch_bounds__(256) void build_csr(const int* __restrict__ psrc,
                                                 const int* __restrict__ pdst,
                                                 const int* __restrict__ bktStart,
                                                 int* __restrict__ offsets,
                                                 float* __restrict__ dinv,
                                                 int* __restrict__ eidx, int N) {
    __shared__ int ncnt[256];
    __shared__ int noff[256];
    __shared__ int cur[256];
    int b = blockIdx.x, t = threadIdx.x;
    int n0 = b << 8;
    int estart = bktStart[b], eend = bktStart[b + 1];
    ncnt[t] = 0;
    __syncthreads();
    for (int e = estart + t; e < eend; e += 256)
        atomicAdd(&ncnt[pdst[e] - n0], 1);
    __syncthreads();
    int c = ncnt[t];
    noff[t] = c;
    __syncthreads();
    for (int off = 1; off < 256; off <<= 1) {
        int u = (t >= off) ? noff[t - off] : 0;
        __syncthreads();
        noff[t] += u;
        __syncthreads();
    }
    int myoff = estart + noff[t] - c;   // exclusive position of node n0+t
    cur[t] = myoff;
    int node = n0 + t;
    if (node < N) {
        offsets[node] = myoff;
        dinv[node] = rsqrtf((float)c + 1.0f);
        if (node == N - 1) offsets[N] = eend;
    }
    __syncthreads();
    for (int e = estart + t; e < eend; e += 256) {
        int d = pdst[e];
        int p = atomicAdd(&cur[d - n0], 1);
        eidx[p] = psrc[e];
    }
}

// ---------------- fp32 -> fp16 convert with per-row dinv scale ----------------
__global__ __launch_bounds__(256) void f2h_scale(const float* __restrict__ in,
                                                 const float* __restrict__ dinv,
                                                 half_t* __restrict__ out, int n4) {
    int i = blockIdx.x * 256 + threadIdx.x;
    if (i < n4) {
        float s = dinv[i >> 5];          // (i*4)/128
        float4 v = ((const float4*)in)[i];
        half4_t o = {(half_t)(v.x * s), (half_t)(v.y * s), (half_t)(v.z * s), (half_t)(v.w * s)};
        ((half4_t*)out)[i] = o;
    }
}

// Wt[c][k] = (half)W[k][c]
__global__ __launch_bounds__(256) void transpose_w(const float* __restrict__ W,
                                                   half_t* __restrict__ Wt, int K, int C) {
    int i = blockIdx.x * 256 + threadIdx.x;
    if (i < K * C) {
        int k = i / C, c = i - k * C;
        Wt[(size_t)c * K + k] = (half_t)W[i];
    }
}

// ---------------- MFMA fp16 GEMM ----------------
// C[r,c] = epilogue( sum_k A[r,k]*Bt[c,k] )
// BIASRELU: relu(acc + bias[c]);  else: acc * dinv[r]
template <int K, int CT, bool BIASRELU>
__global__ __launch_bounds__(256) void gemm_mfma(const half_t* __restrict__ A,
                                                 const half_t* __restrict__ Bt,
                                                 const float* __restrict__ dinv,
                                                 const float* __restrict__ bias,
                                                 half_t* __restrict__ C, int M) {
    constexpr int BK = 64;
    constexpr int LDA = 72;   // halves; 144 B stride -> free 2-way bank aliasing
    __shared__ __align__(16) half_t As[128][LDA];
    __shared__ __align__(16) half_t Bs[64][LDA];

    const int tid = threadIdx.x;
    const int wave = tid >> 6, lane = tid & 63;
    const int wr = wave >> 1, wc = wave & 1;
    const int row0 = blockIdx.y * 128;
    const int col0 = blockIdx.x * 64;
    const int lrow = lane & 15, kq = lane >> 4;

    floatx4 acc[4][2] = {};

    for (int k0 = 0; k0 < K; k0 += BK) {
#pragma unroll
        for (int i = 0; i < 4; ++i) {
            int r = (tid >> 3) + i * 32;
            int kk = (tid & 7) * 8;
            int gr = row0 + r;
            half8 v = {};
            if (gr < M) v = *(const half8*)(A + (size_t)gr * K + k0 + kk);
            *(half8*)&As[r][kk] = v;
        }
#pragma unroll
        for (int i = 0; i < 2; ++i) {
            int n = (tid >> 3) + i * 32;
            int kk = (tid & 7) * 8;
            half8 v = *(const half8*)(Bt + (size_t)(col0 + n) * K + k0 + kk);
            *(half8*)&Bs[n][kk] = v;
        }
        __syncthreads();
#pragma unroll
        for (int ks = 0; ks < 2; ++ks) {
            half8 af[4], bf[2];
#pragma unroll
            for (int i = 0; i < 4; ++i)
                af[i] = *(const half8*)&As[wr * 64 + i * 16 + lrow][ks * 32 + kq * 8];
#pragma unroll
            for (int j = 0; j < 2; ++j)
                bf[j] = *(const half8*)&Bs[wc * 32 + j * 16 + lrow][ks * 32 + kq * 8];
#pragma unroll
            for (int i = 0; i < 4; ++i)
#pragma unroll
                for (int j = 0; j < 2; ++j)
                    acc[i][j] = __builtin_amdgcn_mfma_f32_16x16x32_f16(af[i], bf[j], acc[i][j], 0, 0, 0);
        }
        __syncthreads();
    }

    // C/D layout: col = lane&15, row = (lane>>4)*4 + reg
#pragma unroll
    for (int i = 0; i < 4; ++i) {
#pragma unroll
        for (int r = 0; r < 4; ++r) {
            int grow = row0 + wr * 64 + i * 16 + kq * 4 + r;
            if (grow < M) {
                float s = BIASRELU ? 0.f : dinv[grow];
#pragma unroll
                for (int j = 0; j < 2; ++j) {
                    int gcol = col0 + wc * 32 + j * 16 + lrow;
                    float v = acc[i][j][r];
                    if (BIASRELU) v = fmaxf(v + bias[gcol], 0.f);
                    else          v = v * s;
                    C[(size_t)grow * CT + gcol] = (half_t)v;
                }
            }
        }
    }
}

// ---------------- CSR gather-reduce, 128 fp16 channels ----------------
template <bool OUT16>
__global__ __launch_bounds__(256) void gather128(const half_t* __restrict__ y,
                                                 void* __restrict__ outv,
                                                 const int* __restrict__ offsets,
                                                 const int* __restrict__ eidx,
                                                 const float* __restrict__ dinv,
                                                 const float* __restrict__ bias, int N) {
    int node = blockIdx.x * 8 + (threadIdx.x >> 5);
    if (node >= N) return;
    int c = (threadIdx.x & 31) * 4;

    half4_t sv = *(const half4_t*)(y + (size_t)node * DD + c);   // self loop
    float a0 = (float)sv[0], a1 = (float)sv[1], a2 = (float)sv[2], a3 = (float)sv[3];
    float b0 = 0.f, b1_ = 0.f, b2_ = 0.f, b3 = 0.f;

    int e = offsets[node];
    const int e1 = offsets[node + 1];
    for (; e + 3 < e1; e += 4) {
        int s0 = eidx[e], s1 = eidx[e + 1], s2 = eidx[e + 2], s3 = eidx[e + 3];
        half4_t v0 = *(const half4_t*)(y + (size_t)s0 * DD + c);
        half4_t v1 = *(const half4_t*)(y + (size_t)s1 * DD + c);
        half4_t v2 = *(const half4_t*)(y + (size_t)s2 * DD + c);
        half4_t v3 = *(const half4_t*)(y + (size_t)s3 * DD + c);
        a0 += (float)v0[0]; a1 += (float)v0[1]; a2 += (float)v0[2]; a3 += (float)v0[3];
        b0 += (float)v1[0]; b1_ += (float)v1[1]; b2_ += (float)v1[2]; b3 += (float)v1[3];
        a0 += (float)v2[0]; a1 += (float)v2[1]; a2 += (float)v2[2]; a3 += (float)v2[3];
        b0 += (float)v3[0]; b1_ += (float)v3[1]; b2_ += (float)v3[2]; b3 += (float)v3[3];
    }
    for (; e < e1; ++e) {
        int s0 = eidx[e];
        half4_t v0 = *(const half4_t*)(y + (size_t)s0 * DD + c);
        a0 += (float)v0[0]; a1 += (float)v0[1]; a2 += (float)v0[2]; a3 += (float)v0[3];
    }

    float s = dinv[node];
    float o0 = s * (a0 + b0);
    float o1 = s * (a1 + b1_);
    float o2 = s * (a2 + b2_);
    float o3 = s * (a3 + b3);
    if (OUT16) {
        half4_t o = {(half_t)o0, (half_t)o1, (half_t)o2, (half_t)o3};
        *(half4_t*)((half_t*)outv + (size_t)node * DD + c) = o;
    } else {
        float4 bb = *(const float4*)(bias + c);
        float4 o = make_float4(o0 + bb.x, o1 + bb.y, o2 + bb.z, o3 + bb.w);
        *(float4*)((float*)outv + (size_t)node * DD + c) = o;
    }
}

extern "C" void kernel_launch(void* const* d_in, const int* in_sizes, int n_in,
                              void* d_out, int out_size, void* d_ws, size_t ws_size,
                              hipStream_t stream) {
    const float* emb = (const float*)d_in[0];
    const float* W1  = (const float*)d_in[1];
    const float* b1  = (const float*)d_in[2];
    const float* W2  = (const float*)d_in[3];
    const float* b2  = (const float*)d_in[4];
    const int*   ei  = (const int*)d_in[5];

    const int N = NN;
    const int E = in_sizes[5] / 2;
    const int* src = ei;
    const int* dst = ei + E;

    // workspace layout (bytes)
    char* w = (char*)d_ws;
    float*  dinv = (float*)w;  w += 100032 * 4;
    half_t* zh   = (half_t*)w; w += (size_t)NN * DD * 2;   // emb*dinv; reused as y2
    half_t* g1h  = (half_t*)w; w += (size_t)NN * DD * 2;   // aggregated z
    half_t* x1h  = (half_t*)w; w += (size_t)NN * HH * 2;   // layer-1 output
    half_t* W1t  = (half_t*)w; w += (size_t)DD * HH * 2;
    half_t* W2t  = (half_t*)w; w += (size_t)HH * DD * 2;
    int* offsets = (int*)w;    w += 100032 * 4;
    int* cnt     = (int*)w;    w += (size_t)NBKT * ABLK * 4;
    int* blockOff= (int*)w;    w += (size_t)NBKT * ABLK * 4;
    int* tot     = (int*)w;    w += 512 * 4;
    int* bktStart= (int*)w;    w += 512 * 4;
    int* psrc    = (int*)w;    w += (size_t)E * 4;
    int* pdst    = (int*)w;    w += (size_t)E * 4;
    int* eidx    = (int*)w;
    float* out   = (float*)d_out;
    half_t* y2h  = zh;         // zh dead after gather1

    const int epb = (E + ABLK - 1) / ABLK;

    // 1. CSR build (all per-edge atomics in LDS)
    hipMemsetAsync(tot, 0, NBKT * sizeof(int), stream);
    hist_bkt<<<ABLK, 256, 0, stream>>>(dst, cnt, tot, E, epb);
    scan_bkt<<<1, 512, 0, stream>>>(tot, bktStart, E);
    scan_blkoff<<<NBKT, 128, 0, stream>>>(cnt, bktStart, blockOff);
    part_edges<<<ABLK, 256, 0, stream>>>(src, dst, blockOff, psrc, pdst, E, epb);
    build_csr<<<NBKT, 256, 0, stream>>>(psrc, pdst, bktStart, offsets, dinv, eidx, N);

    // 2. z = emb * dinv[row] (fp16) + weight transposes
    f2h_scale<<<(NN * DD / 4 + 255) / 256, 256, 0, stream>>>(emb, dinv, zh, NN * DD / 4);
    transpose_w<<<(DD * HH + 255) / 256, 256, 0, stream>>>(W1, W1t, DD, HH);
    transpose_w<<<(HH * DD + 255) / 256, 256, 0, stream>>>(W2, W2t, HH, DD);

    const int gy = (N + 127) / 128;
    const int aggBlocks = (N + 7) / 8;

    // 3. layer 1: aggregate-first (g1 = dinv*(z_self + sum z_src)), then GEMM w/ bias+relu
    gather128<true><<<aggBlocks, 256, 0, stream>>>(zh, g1h, offsets, eidx, dinv, nullptr, N);
    gemm_mfma<DD, HH, true><<<dim3(HH / 64, gy), 256, 0, stream>>>(g1h, W1t, dinv, b1, x1h, N);

    // 4. layer 2: GEMM-first (y2 = (x1@W2)*dinv), gather straight into d_out (fp32)
    gemm_mfma<HH, DD, false><<<dim3(DD / 64, gy), 256, 0, stream>>>(x1h, W2t, dinv, nullptr, y2h, N);
    gather128<false><<<aggBlocks, 256, 0, stream>>>(y2h, (void*)out, offsets, eidx, dinv, b2, N);
}